// Round 1
// 289.657 us; speedup vs baseline: 1.3367x; 1.3367x over previous
//
#include <hip/hip_runtime.h>

typedef __bf16 bf16;
typedef __attribute__((ext_vector_type(8))) __bf16 bf16x8;
typedef __attribute__((ext_vector_type(4))) __bf16 bf16x4;
typedef __attribute__((ext_vector_type(4))) float f32x4;
typedef __attribute__((ext_vector_type(4))) float fvec4;

#define NB 2
#define SEQ 2048
#define DM 1024
#define NH 8
#define HD 128

// scale folded into Q projection: 1/sqrt(HD) * log2(e)
#define QSCL (0.08838834764831845f * 1.4426950408889634f)

// ---------------------------------------------------------------------------
// Mask handling: detect encoding (byte-bool vs 32-bit word), pack to 1 bit/elem.
// ---------------------------------------------------------------------------
__global__ void mask_detect(const unsigned int* __restrict__ m,
                            unsigned int* __restrict__ flag)
{
    __shared__ unsigned int s[256];
    unsigned int f = 0;
    for (int i = threadIdx.x; i < 1024; i += 256) {
        const unsigned int w = m[i];
        if ((w & 0xFEFEFEFEu) == 0u && (w & 0xFFFFFF00u) != 0u) f = 1;
    }
    s[threadIdx.x] = f;
    __syncthreads();
    if (threadIdx.x == 0) {
        unsigned int r = 0;
        for (int i = 0; i < 256; i++) r |= s[i];
        *flag = r;
    }
}

__global__ __launch_bounds__(256) void mask_pack(
    const void* __restrict__ m, const unsigned int* __restrict__ flag,
    unsigned long long* __restrict__ bits)
{
    const int gid = blockIdx.x * 256 + threadIdx.x;
    bool mk;
    if (*flag & 1u)
        mk = ((const unsigned char*)m)[gid] != 0;
    else
        mk = ((const unsigned int*)m)[gid] != 0u;
    const unsigned long long b = __ballot(mk);
    if ((threadIdx.x & 63) == 0) bits[gid >> 6] = b;
}

// ---------------------------------------------------------------------------
// Kernel 1: projection GEMM.  Only change from the 387us version: the Q output
// (pz==0) is pre-scaled by 1/sqrt(HD)*log2e so attn's QK^T comes out directly
// in the log2-softmax domain (removes 16 VALU mults/lane/tile in attn).
// ---------------------------------------------------------------------------
__global__ __launch_bounds__(256) void proj_kernel(
    const float* __restrict__ qi, const float* __restrict__ ki,
    const float* __restrict__ vi,
    const float* __restrict__ Wq, const float* __restrict__ Wk,
    const float* __restrict__ Wv,
    const float* __restrict__ bq, const float* __restrict__ bk,
    const float* __restrict__ bv,
    bf16* __restrict__ Qo, bf16* __restrict__ Ko, bf16* __restrict__ Vto)
{
    __shared__ __align__(16) bf16 As[128 * 40];
    __shared__ __align__(16) bf16 Bs[128 * 40];

    const int pz = blockIdx.z;
    const float* X = (pz == 0) ? qi : (pz == 1) ? ki : vi;
    const float* W = (pz == 0) ? Wq : (pz == 1) ? Wk : Wv;
    const float* bias = (pz == 0) ? bq : (pz == 1) ? bk : bv;
    bf16* dst = (pz == 0) ? Qo : (pz == 1) ? Ko : Vto;
    const float oscale = (pz == 0) ? QSCL : 1.0f;

    const int tid  = threadIdx.x;
    const int lane = tid & 63;
    const int w    = tid >> 6;
    const int q16  = lane >> 4;
    const int l15  = lane & 15;

    const int m0 = blockIdx.y * 128;
    const int n0 = blockIdx.x * 128;
    const int wm = (w >> 1) * 64;
    const int wn = (w & 1) * 64;

    const int ar = tid >> 3;
    const int ac = tid & 7;
    const int bc = (tid & 31) * 4;
    const int br = (tid >> 5) * 4;

    f32x4 acc[4][4] = {};

    for (int k0 = 0; k0 < DM; k0 += 32) {
        __syncthreads();
        #pragma unroll
        for (int i = 0; i < 4; i++) {
            const int row = ar + i * 32;
            const fvec4 xv =
                *(const fvec4*)(X + (size_t)(m0 + row) * DM + k0 + ac * 4);
            bf16x4 hv;
            hv.x = (bf16)xv.x; hv.y = (bf16)xv.y;
            hv.z = (bf16)xv.z; hv.w = (bf16)xv.w;
            *(bf16x4*)(As + row * 40 + ac * 4) = hv;
        }
        fvec4 wv[4];
        #pragma unroll
        for (int rr = 0; rr < 4; rr++)
            wv[rr] = *(const fvec4*)(W + (size_t)(k0 + br + rr) * DM + n0 + bc);
        #pragma unroll
        for (int cc = 0; cc < 4; cc++) {
            bf16x4 hv;
            hv.x = (bf16)wv[0][cc]; hv.y = (bf16)wv[1][cc];
            hv.z = (bf16)wv[2][cc]; hv.w = (bf16)wv[3][cc];
            *(bf16x4*)(Bs + (bc + cc) * 40 + br) = hv;
        }
        __syncthreads();

        bf16x8 af[4], bfr[4];
        #pragma unroll
        for (int mi = 0; mi < 4; mi++)
            af[mi] = *(const bf16x8*)(As + (wm + mi * 16 + l15) * 40 + q16 * 8);
        #pragma unroll
        for (int ni = 0; ni < 4; ni++)
            bfr[ni] = *(const bf16x8*)(Bs + (wn + ni * 16 + l15) * 40 + q16 * 8);
        #pragma unroll
        for (int mi = 0; mi < 4; mi++)
            #pragma unroll
            for (int ni = 0; ni < 4; ni++)
                acc[mi][ni] = __builtin_amdgcn_mfma_f32_16x16x32_bf16(
                    af[mi], bfr[ni], acc[mi][ni], 0, 0, 0);
    }

    float bias_v[4];
    #pragma unroll
    for (int ni = 0; ni < 4; ni++)
        bias_v[ni] = bias[n0 + wn + ni * 16 + l15];

    #pragma unroll
    for (int mi = 0; mi < 4; mi++) {
        #pragma unroll
        for (int ni = 0; ni < 4; ni++) {
            const int n  = n0 + wn + ni * 16 + l15;
            const int h  = n >> 7;
            const int hd = n & (HD - 1);
            #pragma unroll
            for (int r = 0; r < 4; r++) {
                const int m = m0 + wm + mi * 16 + q16 * 4 + r;
                const int b = m >> 11;
                const int s = m & (SEQ - 1);
                const float val = (acc[mi][ni][r] + bias_v[ni]) * oscale;
                size_t idx;
                if (pz == 2)
                    idx = ((size_t)(b * NH + h) * HD + hd) * SEQ + s;
                else
                    idx = ((size_t)(b * NH + h) * SEQ + s) * HD + hd;
                dst[idx] = (bf16)val;
            }
        }
    }
}

// ---------------------------------------------------------------------------
// Kernel 2: flash attention, pipelined rewrite.
//   - Double-buffered K/V LDS staged via global_load_lds (16B), issued for
//     tile t+1 at the top of iteration t  ->  ONE barrier per k-tile (was 3).
//   - Linear LDS + XOR chunk swizzle (chunk ^= row&7) applied to BOTH the
//     global source address and the ds_read address (involution, rule #21)
//     -> conflict-free ds_read_b128 (was 8.9M conflict cycles).
//   - Mask bits prefetched one tile ahead as 4x 64-bit words per lane.
//   - Ps (P tile) is wave-private: no barrier between its write and read.
//   - O-rescale skipped via wave vote when no row-max grew.
// ---------------------------------------------------------------------------
__global__ __launch_bounds__(256) void attn_kernel(
    const bf16* __restrict__ Q, const bf16* __restrict__ K,
    const bf16* __restrict__ Vt, const unsigned int* __restrict__ maskbits,
    float* __restrict__ out)
{
    __shared__ __align__(16) bf16 Ks[2][64 * 128];   // 16 KiB per buffer
    __shared__ __align__(16) bf16 Vs[2][128 * 64];   // 16 KiB per buffer
    __shared__ __align__(16) bf16 Ps[4][16 * 72];    // per-wave P tile

    const int tid  = threadIdx.x;
    const int lane = tid & 63;
    const int w    = tid >> 6;
    const int q16  = lane >> 4;
    const int l15  = lane & 15;
    const int l3   = l15 & 7;

    const int b  = blockIdx.z;
    const int h  = blockIdx.y;
    const int q0 = blockIdx.x * 64;
    const int bh = b * NH + h;

    const bf16* Qb = Q  + (size_t)bh * SEQ * HD;
    const bf16* Kb = K  + (size_t)bh * SEQ * HD;
    const bf16* Vb = Vt + (size_t)bh * HD * SEQ;
    const unsigned long long* mb64 =
        (const unsigned long long*)maskbits + (size_t)b * (SEQ * SEQ / 64);
    const int qbase = q0 + w * 16 + q16 * 4;
    const unsigned long long* mrow = mb64 + (size_t)qbase * (SEQ / 64);

    // Q fragments held in registers for the whole kernel (16 q-rows per wave)
    const int qrow_a = q0 + w * 16 + l15;
    bf16x8 qf[4];
    #pragma unroll
    for (int c = 0; c < 4; c++)
        qf[c] = *(const bf16x8*)(Qb + (size_t)qrow_a * HD + c * 32 + q16 * 8);

    f32x4 o[8] = {};
    float m_i[4], l_i[4];
    #pragma unroll
    for (int r = 0; r < 4; r++) { m_i[r] = -__builtin_inff(); l_i[r] = 0.f; }

    const float MASKV = -1.0e6f * QSCL;   // mask applied before scaling in ref

    // --- async stage of one K/V tile into buffer `buf` (source pre-swizzled,
    //     LDS dest linear; read side applies the same XOR) ---
    auto stage = [&](int buf, int k0) {
        bf16* kd = &Ks[buf][0];
        bf16* vd = &Vs[buf][0];
        #pragma unroll
        for (int i = 0; i < 4; i++) {
            const int c   = i * 256 + tid;      // 16B chunk id, 1024 total
            const int row = c >> 4;             // K row (64 rows x 16 chunks)
            const int cir = c & 15;
            const bf16* src =
                Kb + (size_t)(k0 + row) * HD + ((cir ^ (row & 7)) << 3);
            __builtin_amdgcn_global_load_lds(
                (const __attribute__((address_space(1))) void*)src,
                (__attribute__((address_space(3))) void*)(kd + c * 8),
                16, 0, 0);
        }
        #pragma unroll
        for (int i = 0; i < 4; i++) {
            const int c   = i * 256 + tid;      // V: 128 d-rows x 8 chunks
            const int d   = c >> 3;
            const int cir = c & 7;
            const bf16* src =
                Vb + (size_t)d * SEQ + k0 + ((cir ^ (d & 7)) << 3);
            __builtin_amdgcn_global_load_lds(
                (const __attribute__((address_space(1))) void*)src,
                (__attribute__((address_space(3))) void*)(vd + c * 8),
                16, 0, 0);
        }
    };

    // prologue: stage tile 0, prefetch its mask words
    unsigned long long mwn[4];
    stage(0, 0);
    #pragma unroll
    for (int r = 0; r < 4; r++) mwn[r] = mrow[(size_t)r * (SEQ / 64)];
    __syncthreads();   // drains vmcnt -> tile 0 resident

    bf16* Pw = &Ps[w][0];
    int cur = 0;

    for (int kt = 0; kt < SEQ / 64; ++kt) {
        unsigned long long mw[4];
        #pragma unroll
        for (int r = 0; r < 4; r++) mw[r] = mwn[r];

        // issue next tile's staging + mask prefetch FIRST (hides under compute)
        if (kt + 1 < SEQ / 64) stage(cur ^ 1, (kt + 1) * 64);
        const int ktn = (kt + 1) & (SEQ / 64 - 1);
        #pragma unroll
        for (int r = 0; r < 4; r++)
            mwn[r] = mrow[(size_t)r * (SEQ / 64) + ktn];

        const bf16* Ksb = &Ks[cur][0];
        const bf16* Vsb = &Vs[cur][0];

        // QK^T (Q pre-scaled by 1/sqrt(HD)*log2e in proj)
        f32x4 sf[4] = {};
        #pragma unroll
        for (int c = 0; c < 4; c++) {
            #pragma unroll
            for (int nf = 0; nf < 4; nf++) {
                const bf16x8 kf = *(const bf16x8*)(
                    Ksb + (nf * 16 + l15) * 128 + (((c * 4 + q16) ^ l3) << 3));
                sf[nf] = __builtin_amdgcn_mfma_f32_16x16x32_bf16(
                    qf[c], kf, sf[nf], 0, 0, 0);
            }
        }

        // mask (prefetched words; bit j of mw[r] = key k0+j masked for row r)
        #pragma unroll
        for (int nf = 0; nf < 4; nf++)
            #pragma unroll
            for (int r = 0; r < 4; r++) {
                const int mk = (int)((mw[r] >> (nf * 16 + l15)) & 1ull);
                sf[nf][r] = mk ? MASKV : sf[nf][r];
            }

        // online softmax (log2 domain)
        float alpha[4];
        bool need = false;
        #pragma unroll
        for (int r = 0; r < 4; r++) {
            float mx = fmaxf(fmaxf(sf[0][r], sf[1][r]),
                             fmaxf(sf[2][r], sf[3][r]));
            #pragma unroll
            for (int off = 1; off < 16; off <<= 1)
                mx = fmaxf(mx, __shfl_xor(mx, off, 16));
            const float mnew = fmaxf(m_i[r], mx);
            alpha[r] = __builtin_amdgcn_exp2f(m_i[r] - mnew);
            need |= (mnew > m_i[r]);
            m_i[r] = mnew;
            float ps = 0.f;
            #pragma unroll
            for (int nf = 0; nf < 4; nf++) {
                const float p = __builtin_amdgcn_exp2f(sf[nf][r] - mnew);
                sf[nf][r] = p;
                ps += p;
            }
            l_i[r] = l_i[r] * alpha[r] + ps;
        }

        // O rescale only when some row max actually grew (~10% of tiles)
        if (__ballot(need)) {
            #pragma unroll
            for (int df = 0; df < 8; df++)
                #pragma unroll
                for (int r = 0; r < 4; r++)
                    o[df][r] *= alpha[r];
        }

        // P tile: wave-private LDS round-trip (no barrier; DS is in-order)
        #pragma unroll
        for (int nf = 0; nf < 4; nf++)
            #pragma unroll
            for (int r = 0; r < 4; r++)
                Pw[(q16 * 4 + r) * 72 + nf * 16 + l15] = (bf16)sf[nf][r];

        bf16x8 pf[2];
        #pragma unroll
        for (int cc = 0; cc < 2; cc++)
            pf[cc] = *(const bf16x8*)(Pw + l15 * 72 + cc * 32 + q16 * 8);

        // PV
        #pragma unroll
        for (int df = 0; df < 8; df++) {
            #pragma unroll
            for (int cc = 0; cc < 2; cc++) {
                const bf16x8 vf = *(const bf16x8*)(
                    Vsb + (df * 16 + l15) * 64 + (((cc * 4 + q16) ^ l3) << 3));
                o[df] = __builtin_amdgcn_mfma_f32_16x16x32_bf16(
                    pf[cc], vf, o[df], 0, 0, 0);
            }
        }

        // single barrier per tile: drains the async stage (vmcnt) and fences
        // all LDS reads of buf[cur] before it is overwritten next iteration
        __syncthreads();
        cur ^= 1;
    }

    #pragma unroll
    for (int r = 0; r < 4; r++) {
        float ls = l_i[r];
        #pragma unroll
        for (int off = 1; off < 16; off <<= 1)
            ls += __shfl_xor(ls, off, 16);
        l_i[r] = 1.0f / ls;
    }
    #pragma unroll
    for (int df = 0; df < 8; df++) {
        #pragma unroll
        for (int r = 0; r < 4; r++) {
            const int qr = q0 + w * 16 + q16 * 4 + r;
            out[((size_t)b * SEQ + qr) * DM + h * HD + df * 16 + l15] =
                o[df][r] * l_i[r];
        }
    }
}

extern "C" void kernel_launch(void* const* d_in, const int* in_sizes, int n_in,
                              void* d_out, int out_size, void* d_ws, size_t ws_size,
                              hipStream_t stream) {
    const float* q    = (const float*)d_in[0];
    const float* k    = (const float*)d_in[1];
    const float* v    = (const float*)d_in[2];
    const void*  mask = d_in[3];
    const float* Wq   = (const float*)d_in[4];
    const float* bq   = (const float*)d_in[5];
    const float* Wk   = (const float*)d_in[6];
    const float* bk   = (const float*)d_in[7];
    const float* Wv   = (const float*)d_in[8];
    const float* bv   = (const float*)d_in[9];
    float* out = (float*)d_out;

    char* ws = (char*)d_ws;
    unsigned long long* bits = (unsigned long long*)ws;
    const size_t bits_bytes = (size_t)NB * SEQ * SEQ / 8;
    unsigned int* flag = (unsigned int*)(ws + bits_bytes);
    bf16* Qp = (bf16*)(ws + bits_bytes + 256);
    bf16* Kp = Qp + (size_t)NB * SEQ * DM;
    bf16* Vp = Kp + (size_t)NB * SEQ * DM;

    mask_detect<<<1, 256, 0, stream>>>((const unsigned int*)mask, flag);
    mask_pack<<<(NB * SEQ * SEQ) / 256, 256, 0, stream>>>(mask, flag, bits);

    dim3 pgrid(DM / 128, (NB * SEQ) / 128, 3);
    proj_kernel<<<pgrid, 256, 0, stream>>>(q, k, v, Wq, Wk, Wv, bq, bk, bv,
                                           Qp, Kp, Vp);

    dim3 agrid(SEQ / 64, NH, NB);
    attn_kernel<<<agrid, 256, 0, stream>>>(Qp, Kp, Vp,
                                           (const unsigned int*)bits, out);
}